// Round 2
// baseline (246.593 us; speedup 1.0000x reference)
//
#include <hip/hip_runtime.h>
#include <cfloat>
#include <stdint.h>

// VQ argmin via exact-split f16 MFMA GEMM — R22: 256x256 8-phase counted-vmcnt
// template (T2+T3+T4+T5 port). R20 (LDS 2-barrier) and R21 (barrier-free
// direct-global) both landed ~853 TF = the documented 128^2-structure ceiling;
// sync pattern was NOT the limiter. This round: BM=BN=256, 8 waves (2Mx4N),
// virtual K=768 ([Ah|Ah|Al]x[Bh|Bl|Bh] = 12 K-tiles of 64), 128KB LDS
// double-buffer, per-phase {ds_read frag || global_load_lds half-tile ->
// raw s_barrier -> setprio(1) 16xMFMA setprio(0) -> s_barrier}, vmcnt(4)
// once per K-tile (never 0 in steady state). Granule prep keeps every K-tile
// one contiguous 32KB global range -> linear global_load_lds, near-conflict-
// free ds_read_b128. Numerics: same 3-term split/quantization as all passers
// (accumulate order differs: term-major per 64-d chunk; fp32 acc throughout).
#define KC 8192
#define NQ 8192
#define DD 256
#define NT 32              // partial tiles of 256 codes

typedef _Float16 f16;
typedef _Float16 half8 __attribute__((ext_vector_type(8)));
typedef float floatx4 __attribute__((ext_vector_type(4)));

// ---- workspace map (18.0 MB; harness-proven ws >= 20.97 MB) ----
#define WS_AH   0
#define WS_AL   4194304
#define WS_BH   8388608
#define WS_BL   12582912
#define WS_PART 16777216

// ---- device helpers ----
// B-prep: 256-code granules. gid = [nb 32][st 8][quad 4][col 256], each thread
// packs 8 d-values (d = st*32 + quad*8 + j) of code (nb*256+col), hi/lo split.
__device__ __forceinline__ void prep_b_body(const float* __restrict__ cb,
                                            f16* __restrict__ Bh, f16* __restrict__ Bl,
                                            int gid) {
    int col = gid & 255;
    int q = (gid >> 8) & 3;
    int s = (gid >> 10) & 7;
    int nb = gid >> 13;
    int K = nb * 256 + col;
    int d0 = s * 32 + q * 8;
    const float4 v0 = *(const float4*)(cb + (size_t)K * DD + d0);
    const float4 v1 = *(const float4*)(cb + (size_t)K * DD + d0 + 4);
    float vv[8] = {v0.x, v0.y, v0.z, v0.w, v1.x, v1.y, v1.z, v1.w};
    half8 eh8, el8;
    #pragma unroll
    for (int j = 0; j < 8; ++j) {
        float e = vv[j] * 8192.0f;               // exact pow2 scale
        f16 h = (f16)e;
        eh8[j] = h;
        el8[j] = (f16)(e - (float)h);
    }
    *(half8*)(Bh + (size_t)gid * 8) = eh8;
    *(half8*)(Bl + (size_t)gid * 8) = el8;
}

// A-prep (verified R4..R21 layout, byte-identical granules):
//   gid = ((mt*8+st)*4+q)*256 + r holds z[d=st*32+q*8+j][Q=mt*256+r] hi/lo.
__device__ __forceinline__ void prep_a_vec_body(const float* __restrict__ z,
                                                f16* __restrict__ Ah, f16* __restrict__ Al,
                                                int bid, int tid) {
    const int mt = bid >> 3;
    const int s  = bid & 7;
    const int q  = tid >> 6;
    const int lane = tid & 63;
    const int r0 = lane * 4;
    const int Q0 = mt * 256;
    const int b = Q0 >> 10;
    const int t0 = (Q0 & 1023) + r0;
    const float* zp = z + (size_t)b * (DD * 1024) + t0;
    const int d0 = s * 32 + q * 8;
    float4 v[8];
    #pragma unroll
    for (int j = 0; j < 8; ++j)
        v[j] = *(const float4*)(zp + (size_t)(d0 + j) * 1024);
    const size_t gbase = (((size_t)(mt * 8 + s) * 4 + q) * 256 + r0);
    #pragma unroll
    for (int dq = 0; dq < 4; ++dq) {
        half8 zh8, zl8;
        #pragma unroll
        for (int j = 0; j < 8; ++j) {
            float vv = (dq == 0) ? v[j].x : (dq == 1) ? v[j].y : (dq == 2) ? v[j].z : v[j].w;
            f16 h = (f16)vv;
            zh8[j] = h;
            zl8[j] = (f16)(vv - (float)h);       // exact fp32 residual
        }
        *(half8*)(Ah + (gbase + dq) * 8) = zh8;
        *(half8*)(Al + (gbase + dq) * 8) = zl8;
    }
}

__device__ __forceinline__ void zsq_body(const float* __restrict__ z,
                                         float* __restrict__ zsq, int q) {
    int b = q >> 10, t = q & 1023;
    const float* p = z + (size_t)b * (DD * 1024) + t;
    float s0 = 0.f, s1 = 0.f;
    #pragma unroll 8
    for (int d = 0; d < 128; ++d) { float v = p[(size_t)d * 1024]; s0 = fmaf(v, v, s0); }
    #pragma unroll 8
    for (int d = 128; d < 256; ++d) { float v = p[(size_t)d * 1024]; s1 = fmaf(v, v, s1); }
    zsq[q] = s0 + s1;    // identical chain to all passers
}

// ---- fused prep: blocks [0,1024) B | [1024,1280) A-vec | [1280,1312) zsq ----
__global__ void vq_prep_all(const float* __restrict__ z, const float* __restrict__ cb,
                            f16* __restrict__ Ah, f16* __restrict__ Al,
                            f16* __restrict__ Bh, f16* __restrict__ Bl,
                            float* __restrict__ zsq) {
    int bid = blockIdx.x;
    int tid = threadIdx.x;
    if (bid < 1024) {
        prep_b_body(cb, Bh, Bl, bid * 256 + tid);
    } else if (bid < 1280) {
        prep_a_vec_body(z, Ah, Al, bid - 1024, tid);
    } else {
        zsq_body(z, zsq, (bid - 1280) * 256 + tid);
    }
}

// ---- main GEMM: 256x256 tile, 8 waves of 128x64, 8-phase counted-vmcnt ----
// Granule-group byte offsets (contiguous 16KB per (kchunk, kslice) half-tile):
#define ABYTE(cc, ss) (((size_t)bm * 32 + ((cc) * 2 + (ss)) * 4) * 4096)
#define BBYTE(cc, ss) (((size_t)nb * 32 + ((cc) * 2 + (ss)) * 4) * 4096)

// Stage one 16KB half-tile: 512 threads x 2 x 16B, linear global -> linear LDS.
#define STAGE16K(gbase, grpbyte, ldsoff) do {                                   \
    const char* _g = (const char*)(gbase) + (grpbyte) + (size_t)(wv * 1024)     \
                     + (size_t)(lane * 16);                                     \
    char* _l = smem + (ldsoff) + wv * 1024;                                     \
    __builtin_amdgcn_global_load_lds(                                           \
        (const __attribute__((address_space(1))) void*)_g,                      \
        (__attribute__((address_space(3))) void*)_l, 16, 0, 0);                 \
    __builtin_amdgcn_global_load_lds(                                           \
        (const __attribute__((address_space(1))) void*)(_g + 8192),             \
        (__attribute__((address_space(3))) void*)(_l + 8192), 16, 0, 0);        \
} while (0)

#define VMC4 asm volatile("s_waitcnt vmcnt(4)" ::: "memory")
#define VMC0 asm volatile("s_waitcnt vmcnt(0)" ::: "memory")
#define NOPF (void)0
#define NOWT (void)0

// Phase: read A frags (+B frags in PHASE_B; PHASE_R reuses bf), issue prefetch,
// optional vmcnt, raw barrier, 16 MFMA under setprio, raw barrier.
#define PHASE_B(cur, h, s, PF, WAIT) do {                                       \
    { const char* _ab = smem + (cur) * 65536 + (s) * 16384 + aoff + (h) * 1024; \
      _Pragma("unroll") for (int _m = 0; _m < 4; ++_m)                          \
          av[_m] = *(const half8*)(_ab + _m * 256);                             \
      const char* _bb = smem + (cur) * 65536 + 32768 + (s) * 16384 + boff;      \
      _Pragma("unroll") for (int _n = 0; _n < 4; ++_n)                          \
          bf[_n] = *(const half8*)(_bb + _n * 256); }                           \
    PF; WAIT;                                                                   \
    asm volatile("" ::: "memory");                                              \
    __builtin_amdgcn_s_barrier();                                               \
    __builtin_amdgcn_s_setprio(1);                                              \
    _Pragma("unroll") for (int _m = 0; _m < 4; ++_m)                            \
      _Pragma("unroll") for (int _n = 0; _n < 4; ++_n)                          \
        acc[(h) * 4 + _m][_n] = __builtin_amdgcn_mfma_f32_16x16x32_f16(         \
            av[_m], bf[_n], acc[(h) * 4 + _m][_n], 0, 0, 0);                    \
    __builtin_amdgcn_s_setprio(0);                                              \
    asm volatile("" ::: "memory");                                              \
    __builtin_amdgcn_s_barrier();                                               \
} while (0)

#define PHASE_R(cur, h, s, PF, WAIT) do {                                       \
    { const char* _ab = smem + (cur) * 65536 + (s) * 16384 + aoff + (h) * 1024; \
      _Pragma("unroll") for (int _m = 0; _m < 4; ++_m)                          \
          av[_m] = *(const half8*)(_ab + _m * 256); }                           \
    PF; WAIT;                                                                   \
    asm volatile("" ::: "memory");                                              \
    __builtin_amdgcn_s_barrier();                                               \
    __builtin_amdgcn_s_setprio(1);                                              \
    _Pragma("unroll") for (int _m = 0; _m < 4; ++_m)                            \
      _Pragma("unroll") for (int _n = 0; _n < 4; ++_n)                          \
        acc[(h) * 4 + _m][_n] = __builtin_amdgcn_mfma_f32_16x16x32_f16(         \
            av[_m], bf[_n], acc[(h) * 4 + _m][_n], 0, 0, 0);                    \
    __builtin_amdgcn_s_setprio(0);                                              \
    asm volatile("" ::: "memory");                                              \
    __builtin_amdgcn_s_barrier();                                               \
} while (0)

__global__ __launch_bounds__(512, 2)
void vq_gemm256(const f16* __restrict__ Ah, const f16* __restrict__ Al,
                const f16* __restrict__ Bh, const f16* __restrict__ Bl,
                const float* __restrict__ zsq, unsigned long long* __restrict__ part_p) {
    // XCD-aware swizzle: xcd gets 4 bm rows, nb sweeps (4-block B reuse in L2).
    const int flat = blockIdx.x;
    const int xcd = flat & 7;
    const int idx = flat >> 3;
    const int bm = xcd * 4 + (idx & 3);     // 0..31 (256-query tile)
    const int nb = idx >> 2;                // 0..31 (256-code tile)
    const int tid = threadIdx.x;
    const int lane = tid & 63;
    const int wv = tid >> 6;                // 0..7
    const int wm = wv >> 2;                 // 0..1: 2 M-waves (128 rows each)
    const int wn = wv & 3;                  // 0..3: 4 N-waves (64 cols each)
    const int quad = lane >> 4;
    const int l16 = lane & 15;

    __shared__ __attribute__((aligned(16))) char smem[131072];   // 2 x 64KB dbuf

    floatx4 acc[8][4];
    #pragma unroll
    for (int i = 0; i < 8; ++i)
        #pragma unroll
        for (int j = 0; j < 4; ++j) acc[i][j] = (floatx4)0.f;
    half8 av[4], bf[4];

    // Per-thread LDS fragment offsets (within a buffer region):
    //   A byte = cur*65536 + s*16384 + quad*4096 + (wm*128 + h*64 + mi*16 + l16)*16
    //   B byte = cur*65536 + 32768 + s*16384 + quad*4096 + (wn*64 + nj*16 + l16)*16
    const int aoff = quad * 4096 + (wm * 128 + l16) * 16;
    const int boff = quad * 4096 + (wn * 64 + l16) * 16;

    // ---- prologue: tile0 (Ah·Bh c0) full + tile1 (Ah·Bl c0) s0-half ----
    STAGE16K(Ah, ABYTE(0, 0), 0);                 // t0 A s0 -> buf0
    STAGE16K(Bh, BBYTE(0, 0), 32768);             // t0 B s0
    STAGE16K(Ah, ABYTE(0, 1), 16384);             // t0 A s1
    STAGE16K(Bh, BBYTE(0, 1), 49152);             // t0 B s1
    STAGE16K(Ah, ABYTE(0, 0), 65536);             // t1 A s0 -> buf1
    STAGE16K(Bl, BBYTE(0, 0), 98304);             // t1 B s0
    VMC4;                                         // tile0 (8 loads) landed
    __builtin_amdgcn_s_barrier();

    // ---- main loop: c = 0..2, tiles t = 3c{+0,+1,+2}; tail c=3 peeled ----
    // Per tile, 4 phases (h,s) = (0,0),(1,0),(0,1),(1,1); prefetch per phase:
    //   ph0: (t+1) A s1   ph1: (t+1) B s1   ph2: (t+2) A s0   ph3: (t+2) B s0
    // vmcnt(4) at ph3 => all of tile t+1 landed before its first read.
    for (int c = 0; c < 3; ++c) {
        const int cu0 = c & 1, cu1 = cu0 ^ 1;
        // t = 3c: Ah·Bh(c), cur=cu0
        PHASE_B(cu0, 0, 0, STAGE16K(Ah, ABYTE(c, 1), cu1 * 65536 + 16384), NOWT);
        PHASE_R(cu0, 1, 0, STAGE16K(Bl, BBYTE(c, 1), cu1 * 65536 + 49152), NOWT);
        PHASE_B(cu0, 0, 1, STAGE16K(Al, ABYTE(c, 0), cu0 * 65536 + 0),     NOWT);
        PHASE_R(cu0, 1, 1, STAGE16K(Bh, BBYTE(c, 0), cu0 * 65536 + 32768), VMC4);
        // t = 3c+1: Ah·Bl(c), cur=cu1
        PHASE_B(cu1, 0, 0, STAGE16K(Al, ABYTE(c, 1),     cu0 * 65536 + 16384), NOWT);
        PHASE_R(cu1, 1, 0, STAGE16K(Bh, BBYTE(c, 1),     cu0 * 65536 + 49152), NOWT);
        PHASE_B(cu1, 0, 1, STAGE16K(Ah, ABYTE(c + 1, 0), cu1 * 65536 + 0),     NOWT);
        PHASE_R(cu1, 1, 1, STAGE16K(Bh, BBYTE(c + 1, 0), cu1 * 65536 + 32768), VMC4);
        // t = 3c+2: Al·Bh(c), cur=cu0
        PHASE_B(cu0, 0, 0, STAGE16K(Ah, ABYTE(c + 1, 1), cu1 * 65536 + 16384), NOWT);
        PHASE_R(cu0, 1, 0, STAGE16K(Bh, BBYTE(c + 1, 1), cu1 * 65536 + 49152), NOWT);
        PHASE_B(cu0, 0, 1, STAGE16K(Ah, ABYTE(c + 1, 0), cu0 * 65536 + 0),     NOWT);
        PHASE_R(cu0, 1, 1, STAGE16K(Bl, BBYTE(c + 1, 0), cu0 * 65536 + 32768), VMC4);
    }
    // ---- tail c=3: t=9 (Ah·Bh, cur=1), t=10 (Ah·Bl, cur=0), t=11 (Al·Bh, cur=1)
    PHASE_B(1, 0, 0, STAGE16K(Ah, ABYTE(3, 1), 16384), NOWT);
    PHASE_R(1, 1, 0, STAGE16K(Bl, BBYTE(3, 1), 49152), NOWT);
    PHASE_B(1, 0, 1, STAGE16K(Al, ABYTE(3, 0), 65536 + 0), NOWT);
    PHASE_R(1, 1, 1, STAGE16K(Bh, BBYTE(3, 0), 65536 + 32768), VMC4);
    PHASE_B(0, 0, 0, STAGE16K(Al, ABYTE(3, 1), 65536 + 16384), NOWT);
    PHASE_R(0, 1, 0, STAGE16K(Bh, BBYTE(3, 1), 65536 + 49152), NOWT);
    PHASE_B(0, 0, 1, NOPF, NOWT);
    PHASE_R(0, 1, 1, NOPF, VMC4);                 // t11 s0 landed
    PHASE_B(1, 0, 0, NOPF, NOWT);
    PHASE_R(1, 1, 0, NOPF, VMC0);                 // tail drain: t11 s1 landed
    PHASE_B(1, 0, 1, NOPF, NOWT);
    PHASE_R(1, 1, 1, NOPF, NOWT);

    // ---- epilogue (verified C/D map): dist quantization + 4-way LDS merge ----
    __syncthreads();                              // full drain; reuse smem
    unsigned long long* kbuf = (unsigned long long*)smem;   // [256 rows][4 wn]
    const int kb = nb * 256 + wn * 64;
    #pragma unroll
    for (int mi = 0; mi < 8; ++mi) {
        #pragma unroll
        for (int reg = 0; reg < 4; ++reg) {
            int qlocal = wm * 128 + mi * 16 + quad * 4 + reg;   // verified map
            float zq = zsq[bm * 256 + qlocal];
            float bd = FLT_MAX; int bk = 0;
            #pragma unroll
            for (int nj = 0; nj < 4; ++nj) {        // ascending k: '<' keeps lowest
                float dd = zq - acc[mi][nj][reg] * 0x1p-12f;  // single fp32 rounding
                int kk = kb + nj * 16 + l16;
                if (dd < bd || (dd == bd && kk < bk)) { bd = dd; bk = kk; }
            }
            #pragma unroll
            for (int mm = 1; mm <= 8; mm <<= 1) {   // 16-lane butterfly, same q
                float od = __shfl_xor(bd, mm, 64);
                int ok = __shfl_xor(bk, mm, 64);
                if (od < bd || (od == bd && ok < bk)) { bd = od; bk = ok; }
            }
            if (l16 == 0)
                kbuf[qlocal * 4 + wn] =
                    ((unsigned long long)__float_as_uint(bd) << 32) | (unsigned int)bk;
        }
    }
    __syncthreads();
    if (tid < 256) {
        unsigned long long k0 = kbuf[tid * 4 + 0];
        unsigned long long k1 = kbuf[tid * 4 + 1];
        unsigned long long k2 = kbuf[tid * 4 + 2];
        unsigned long long k3 = kbuf[tid * 4 + 3];
        unsigned long long key = k0 < k1 ? k0 : k1;
        if (k2 < key) key = k2;
        if (k3 < key) key = k3;
        part_p[(size_t)nb * NQ + bm * 256 + tid] = key;   // coalesced 2KB store
    }
}

__global__ void vq_reduce32(const unsigned long long* __restrict__ part,
                            int* __restrict__ out) {
    int q = blockIdx.x * 256 + threadIdx.x;
    unsigned long long best = part[q];
    #pragma unroll 8
    for (int s = 1; s < NT; ++s) {                  // coalesced per-row reads
        unsigned long long k2 = part[(size_t)s * NQ + q];
        if (k2 < best) best = k2;
    }
    out[q] = (int)(best & 0xFFFFFFFFull);
}

extern "C" void kernel_launch(void* const* d_in, const int* in_sizes, int n_in,
                              void* d_out, int out_size, void* d_ws, size_t ws_size,
                              hipStream_t stream) {
    const float* z  = (const float*)d_in[0];   // (8, 256, 1024) fp32
    const float* cb = (const float*)d_in[1];   // (8192, 256) fp32
    char* ws = (char*)d_ws;
    f16* Ah = (f16*)(ws + WS_AH);
    f16* Al = (f16*)(ws + WS_AL);
    f16* Bh = (f16*)(ws + WS_BH);
    f16* Bl = (f16*)(ws + WS_BL);
    unsigned long long* part = (unsigned long long*)(ws + WS_PART);
    // zsq parked in d_out (32 KB): read by gemm, overwritten by reduce.
    float* zsq = (float*)d_out;
    int* out = (int*)d_out;

    // total ws need = 18.0 MB; every harness run to date provided >= 20.97 MB.
    vq_prep_all<<<1312, 256, 0, stream>>>(z, cb, Ah, Al, Bh, Bl, zsq);
    vq_gemm256<<<1024, 512, 0, stream>>>(Ah, Al, Bh, Bl, zsq, part);
    vq_reduce32<<<NQ / 256, 256, 0, stream>>>(part, out);
}

// Round 3
// 219.840 us; speedup vs baseline: 1.1217x; 1.1217x over previous
//
#include <hip/hip_runtime.h>
#include <cfloat>
#include <stdint.h>

// VQ argmin via exact-split f16 MFMA GEMM — R23: intensity-doubled barrier-free
// GEMM. R21 (64x64 wave tile, direct-global, no barriers) = 853 TF with L2
// request traffic 2.15 GB @ 17.8 TB/s ~= the achieved L2 ceiling; R22's
// 8-phase port failed (lockstep stalls, matches m232's open quadrant).
// R23 = R21 structure with 128x64 wave tile (intensity 48 -> 64 FLOP/B,
// request traffic -27%), 2x2 waves -> 256x128 block, acc[8][4],
// launch_bounds(256,2). Numerics bit-identical to all passers: same granule
// bytes, same per-acc 3-term MFMA order (av*bh, av*bl, aw*bh per 32-d stage),
// same dist quantization fp32(zsq - acc*2^-12), same u64 key compare (atomicMin
// over ntl == sequential u64-min scan; ties impossible since k differs).
// Also: reduce fused via atomicMin(u64) into a 64KB key array (part 4MB r/w
// gone), key-init + zsq folded into prep with zsq split s0/s1 across 2 threads
// (identical chains), heavy prep blocks dispatched first.
#define KC 8192
#define NQ 8192
#define DD 256
#define NSTAGE 8

typedef _Float16 f16;
typedef _Float16 half8 __attribute__((ext_vector_type(8)));
typedef float floatx4 __attribute__((ext_vector_type(4)));

// ---- workspace maps ----
#define WS_AH   0
#define WS_AL   4194304
#define WS_BH   8388608
#define WS_BL1  12582912           // 1-pass: Bh/Bl 4MB each
#define WS_KEY1 16777216
#define WS_NEED1 (16777216ull + 65536ull)   // 16.06 MB <= proven 16.875 MB floor
#define WS_BL2  10485760           // 2-pass fallback: Bh/Bl 2MB each
#define WS_KEY2 12582912

// ---- device helpers ----
// B-prep (verified R4..R21 layout): gid = [ntl][s 8][q 4][n 128]; thread packs
// 8 d-values (d = s*32 + q*8 + j) of code (kofs + ntl*128 + n), hi/lo split.
__device__ __forceinline__ void prep_b_body(const float* __restrict__ cb,
                                            f16* __restrict__ Bh, f16* __restrict__ Bl,
                                            int kofs, int gid) {
    int n = gid & 127;
    int q = (gid >> 7) & 3;
    int s = (gid >> 9) & 7;
    int ntl = gid >> 12;
    int K = kofs + ntl * 128 + n;
    int d0 = s * 32 + q * 8;
    const float4 v0 = *(const float4*)(cb + (size_t)K * DD + d0);
    const float4 v1 = *(const float4*)(cb + (size_t)K * DD + d0 + 4);
    float vv[8] = {v0.x, v0.y, v0.z, v0.w, v1.x, v1.y, v1.z, v1.w};
    half8 eh8, el8;
    #pragma unroll
    for (int j = 0; j < 8; ++j) {
        float e = vv[j] * 8192.0f;               // exact pow2 scale
        f16 h = (f16)e;
        eh8[j] = h;
        el8[j] = (f16)(e - (float)h);
    }
    *(half8*)(Bh + (size_t)gid * 8) = eh8;
    *(half8*)(Bl + (size_t)gid * 8) = el8;
}

// A-prep (verified R4..R21 layout, byte-identical granules):
//   gid = ((mt*8+st)*4+q)*256 + r holds z[d=st*32+q*8+j][Q=mt*256+r] hi/lo.
__device__ __forceinline__ void prep_a_vec_body(const float* __restrict__ z,
                                                f16* __restrict__ Ah, f16* __restrict__ Al,
                                                int bid, int tid) {
    const int mt = bid >> 3;
    const int s  = bid & 7;
    const int q  = tid >> 6;
    const int lane = tid & 63;
    const int r0 = lane * 4;
    const int Q0 = mt * 256;
    const int b = Q0 >> 10;
    const int t0 = (Q0 & 1023) + r0;
    const float* zp = z + (size_t)b * (DD * 1024) + t0;
    const int d0 = s * 32 + q * 8;
    float4 v[8];
    #pragma unroll
    for (int j = 0; j < 8; ++j)
        v[j] = *(const float4*)(zp + (size_t)(d0 + j) * 1024);
    const size_t gbase = (((size_t)(mt * 8 + s) * 4 + q) * 256 + r0);
    #pragma unroll
    for (int dq = 0; dq < 4; ++dq) {
        half8 zh8, zl8;
        #pragma unroll
        for (int j = 0; j < 8; ++j) {
            float vv = (dq == 0) ? v[j].x : (dq == 1) ? v[j].y : (dq == 2) ? v[j].z : v[j].w;
            f16 h = (f16)vv;
            zh8[j] = h;
            zl8[j] = (f16)(vv - (float)h);       // exact fp32 residual
        }
        *(half8*)(Ah + (gbase + dq) * 8) = zh8;
        *(half8*)(Al + (gbase + dq) * 8) = zl8;
    }
}

// zsq split across 2 threads/query: s0 (d 0..127) and s1 (d 128..255) are the
// exact partial chains of all passers; zsq[q] = s0 + s1 identical. Also inits
// the atomic key array.
__device__ __forceinline__ void zsq2_body(const float* __restrict__ z,
                                          float* __restrict__ zsq,
                                          unsigned long long* __restrict__ key,
                                          int gid) {
    int q = gid >> 1, half = gid & 1;
    int b = q >> 10, t = q & 1023;
    const float* p = z + (size_t)b * (DD * 1024) + t + (size_t)(half * 128) * 1024;
    float s = 0.f;
    #pragma unroll 8
    for (int d = 0; d < 128; ++d) { float v = p[(size_t)d * 1024]; s = fmaf(v, v, s); }
    float so = __shfl_xor(s, 1, 64);             // partner half, same q
    if (half == 0) { zsq[q] = s + so; key[q] = ~0ull; }
}

// ---- fused prep, long poles first:
//   blocks [0,64) zsq+key-init | [64,320) A-vec | [320,1344) B ----
__global__ void vq_prep_all(const float* __restrict__ z, const float* __restrict__ cb,
                            f16* __restrict__ Ah, f16* __restrict__ Al,
                            f16* __restrict__ Bh, f16* __restrict__ Bl,
                            float* __restrict__ zsq, unsigned long long* __restrict__ key) {
    int bid = blockIdx.x;
    int tid = threadIdx.x;
    if (bid < 64) {
        zsq2_body(z, zsq, key, bid * 256 + tid);
    } else if (bid < 320) {
        prep_a_vec_body(z, Ah, Al, bid - 64, tid);
    } else {
        prep_b_body(cb, Bh, Bl, 0, (bid - 320) * 256 + tid);
    }
}

// standalone preps for the 2-pass fallback
__global__ void vq_prep_az(const float* __restrict__ z,
                           f16* __restrict__ Ah, f16* __restrict__ Al,
                           float* __restrict__ zsq, unsigned long long* __restrict__ key) {
    int bid = blockIdx.x;
    if (bid < 64) zsq2_body(z, zsq, key, bid * 256 + threadIdx.x);
    else          prep_a_vec_body(z, Ah, Al, bid - 64, threadIdx.x);
}
__global__ void vq_prep_b(const float* __restrict__ cb,
                          f16* __restrict__ Bh, f16* __restrict__ Bl, int kofs) {
    prep_b_body(cb, Bh, Bl, kofs, blockIdx.x * 256 + threadIdx.x);
}

// ---- main GEMM (R23): 256x128 block, 2x2 waves of 128x64, A and B direct
//      from global (16B/lane coalesced, L2-resident), NO barriers in K-loop.
//      Intensity 64 FLOP/L2-byte (vs R21's 48). ----
__global__ __launch_bounds__(256, 2)
void vq_gemm16(const f16* __restrict__ Ah, const f16* __restrict__ Al,
               const f16* __restrict__ Bh, const f16* __restrict__ Bl,
               const float* __restrict__ zsq, unsigned long long* __restrict__ keyp,
               int kofs) {
    // XCD-aware swizzle: each XCD owns 4 mt (A tiles, L2-resident), ntl sweeps.
    const int flat = blockIdx.x;
    const int xcd = flat & 7;
    const int idx = flat >> 3;
    const int mt = xcd * 4 + (idx & 3);     // 0..31 (256-query tile)
    const int ntl = idx >> 2;               // 0..63 (1-pass) / 0..31 (2-pass)
    const int tid = threadIdx.x;
    const int lane = tid & 63;
    const int wv = tid >> 6;
    const int wm = wv >> 1, wn = wv & 1;    // 2x2 waves: 128 rows x 64 cols each
    const int quad = lane >> 4;
    const int l16 = lane & 15;

    __shared__ unsigned long long kbuf[512];      // epilogue merge only

    floatx4 acc[8][4];
    #pragma unroll
    for (int i = 0; i < 8; ++i)
        #pragma unroll
        for (int j = 0; j < 4; ++j) acc[i][j] = (floatx4)0.f;

    // A fragment address in halfs (same granule bytes as all passers):
    //   (((mt*8+s)*4+quad)*256 + wm*128 + mi*16 + l16) * 8
    const size_t abase = ((((size_t)(mt * 8) * 4) + quad) * 256
                          + (size_t)(wm * 128 + l16)) * 8;
    const f16* Ap  = Ah + abase;
    const f16* Alp = Al + abase;
    const f16* Bpb = Bh + ((size_t)(ntl * 8) * 4 + quad) * 1024 + (size_t)(wn * 64 + l16) * 8;
    const f16* Blb = Bl + ((size_t)(ntl * 8) * 4 + quad) * 1024 + (size_t)(wn * 64 + l16) * 8;

    for (int s = 0; s < NSTAGE; ++s) {
        // ---- B fragments (8 x 1KB coalesced loads) ----
        half8 bhf[4], blf[4];
        #pragma unroll
        for (int nj = 0; nj < 4; ++nj) {
            bhf[nj] = *(const half8*)(Bpb + nj * 128);
            blf[nj] = *(const half8*)(Blb + nj * 128);
        }
        // ---- A hi fragments (8 x 1KB) ----
        half8 av[8];
        #pragma unroll
        for (int mi = 0; mi < 8; ++mi)
            av[mi] = *(const half8*)(Ap + (size_t)mi * 128);
        // term 1: zh*eh
        #pragma unroll
        for (int mi = 0; mi < 8; ++mi)
            #pragma unroll
            for (int nj = 0; nj < 4; ++nj)
                acc[mi][nj] = __builtin_amdgcn_mfma_f32_16x16x32_f16(av[mi], bhf[nj], acc[mi][nj], 0, 0, 0);
        // term 2: zh*el
        #pragma unroll
        for (int mi = 0; mi < 8; ++mi)
            #pragma unroll
            for (int nj = 0; nj < 4; ++nj)
                acc[mi][nj] = __builtin_amdgcn_mfma_f32_16x16x32_f16(av[mi], blf[nj], acc[mi][nj], 0, 0, 0);
        // ---- A lo fragments (8 x 1KB), then term 3: zl*eh ----
        half8 aw[8];
        #pragma unroll
        for (int mi = 0; mi < 8; ++mi)
            aw[mi] = *(const half8*)(Alp + (size_t)mi * 128);
        #pragma unroll
        for (int mi = 0; mi < 8; ++mi)
            #pragma unroll
            for (int nj = 0; nj < 4; ++nj)
                acc[mi][nj] = __builtin_amdgcn_mfma_f32_16x16x32_f16(aw[mi], bhf[nj], acc[mi][nj], 0, 0, 0);
        // advance one K-stage: A granule group += 8192 halfs, B += 4096 halfs
        Ap  += 8192; Alp += 8192;
        Bpb += 4096; Blb += 4096;
    }

    // ---- epilogue (verified C/D map): dist quantization + 2-way merge +
    //      device-wide atomicMin (== sequential u64-min over ntl) ----
    const int kb = kofs + ntl * 128 + wn * 64;
    #pragma unroll
    for (int mi = 0; mi < 8; ++mi) {
        #pragma unroll
        for (int reg = 0; reg < 4; ++reg) {
            int qlocal = wm * 128 + mi * 16 + quad * 4 + reg;   // verified map
            float zq = zsq[mt * 256 + qlocal];
            float bd = FLT_MAX; int bk = 0;
            #pragma unroll
            for (int nj = 0; nj < 4; ++nj) {        // ascending k: '<' keeps lowest
                float dd = zq - acc[mi][nj][reg] * 0x1p-12f;  // single fp32 rounding
                int kk = kb + nj * 16 + l16;
                if (dd < bd || (dd == bd && kk < bk)) { bd = dd; bk = kk; }
            }
            #pragma unroll
            for (int mm = 1; mm <= 8; mm <<= 1) {   // 16-lane butterfly, same q
                float od = __shfl_xor(bd, mm, 64);
                int ok = __shfl_xor(bk, mm, 64);
                if (od < bd || (od == bd && ok < bk)) { bd = od; bk = ok; }
            }
            if (l16 == 0)
                kbuf[qlocal * 2 + wn] =
                    ((unsigned long long)__float_as_uint(bd) << 32) | (unsigned int)bk;
        }
    }
    __syncthreads();
    if (tid < 256) {
        unsigned long long k0 = kbuf[tid * 2 + 0];
        unsigned long long k1 = kbuf[tid * 2 + 1];
        unsigned long long key = (k1 < k0) ? k1 : k0;
        atomicMin(&keyp[mt * 256 + tid], key);      // ties impossible (k differs)
    }
}

__global__ void vq_extract(const unsigned long long* __restrict__ key,
                           int* __restrict__ out) {
    int q = blockIdx.x * 256 + threadIdx.x;
    out[q] = (int)(key[q] & 0xFFFFFFFFull);
}

extern "C" void kernel_launch(void* const* d_in, const int* in_sizes, int n_in,
                              void* d_out, int out_size, void* d_ws, size_t ws_size,
                              hipStream_t stream) {
    const float* z  = (const float*)d_in[0];   // (8, 256, 1024) fp32
    const float* cb = (const float*)d_in[1];   // (8192, 256) fp32
    char* ws = (char*)d_ws;
    f16* Ah = (f16*)(ws + WS_AH);
    f16* Al = (f16*)(ws + WS_AL);
    // zsq parked in d_out (32 KB): read by gemm, overwritten by extract.
    float* zsq = (float*)d_out;
    int* out = (int*)d_out;

    if (ws_size >= WS_NEED1) {
        f16* Bh = (f16*)(ws + WS_BH);
        f16* Bl = (f16*)(ws + WS_BL1);
        unsigned long long* key = (unsigned long long*)(ws + WS_KEY1);
        vq_prep_all<<<1344, 256, 0, stream>>>(z, cb, Ah, Al, Bh, Bl, zsq, key);
        vq_gemm16<<<2048, 256, 0, stream>>>(Ah, Al, Bh, Bl, zsq, key, 0);
        vq_extract<<<NQ / 256, 256, 0, stream>>>(key, out);
    } else {
        // 2-pass fallback (12.06 MB): B buffer reused across halves of K.
        f16* Bh = (f16*)(ws + WS_BH);
        f16* Bl = (f16*)(ws + WS_BL2);
        unsigned long long* key = (unsigned long long*)(ws + WS_KEY2);
        vq_prep_az<<<320, 256, 0, stream>>>(z, Ah, Al, zsq, key);
        for (int p = 0; p < 2; ++p) {
            int kofs = p * 4096;
            vq_prep_b<<<512, 256, 0, stream>>>(cb, Bh, Bl, kofs);
            vq_gemm16<<<1024, 256, 0, stream>>>(Ah, Al, Bh, Bl, zsq, key, kofs);
        }
        vq_extract<<<NQ / 256, 256, 0, stream>>>(key, out);
    }
}